// Round 11
// baseline (369.922 us; speedup 1.0000x reference)
//
#include <hip/hip_runtime.h>

#define NN 100000
#define NE 1600000
#define INC 128
#define TE 32
#define OC 128
#define NR 8
#define NBASES 8
#define FT 160
#define KP 168          // padded K stride (bf16 elems) for LDS feat tile
#define KW 160          // unpadded K stride for global Wt
#define TN 64           // nodes per bucket (two 32-node tiles per k_mega block)
#define NBKT 1563       // ceil(NN/64) dst buckets
#define NCH 256         // edge chunks (full-CU coverage)
#define EPB 6250        // edges per chunk (256*6250 = NE exactly)
#define CAP 1536        // per-bucket edge cap (mean 1024, +16 sigma)

typedef float f32x4 __attribute__((ext_vector_type(4)));
typedef float f32x2 __attribute__((ext_vector_type(2)));
typedef __bf16 bf16x8 __attribute__((ext_vector_type(8)));

__device__ __forceinline__ unsigned f2bf1(float f) {
    unsigned u = __float_as_uint(f);
    return (u + 0x7fffu + ((u >> 16) & 1u)) >> 16;   // RNE to bf16
}

__device__ __forceinline__ float bflo(unsigned u) { return __uint_as_float(u << 16); }
__device__ __forceinline__ float bfhi(unsigned u) { return __uint_as_float(u & 0xFFFF0000u); }

// pack two f32 -> bf16 pair (S0 -> low 16, S1 -> high 16), RNE — 1 instr
__device__ __forceinline__ unsigned cvtpk(float a, float b) {
    unsigned r;
    asm("v_cvt_pk_bf16_f32 %0, %1, %2" : "=v"(r) : "v"(a), "v"(b));
    return r;
}

// exclusive block scan over 256 per-thread values (Hillis-Steele in LDS)
__device__ __forceinline__ int bscan_excl(int v, int* tmp) {
    int tid = threadIdx.x;
    tmp[tid] = v; __syncthreads();
#pragma unroll
    for (int d = 1; d < 256; d <<= 1) {
        int t = (tid >= d) ? tmp[tid - d] : 0;
        __syncthreads();
        tmp[tid] += t;
        __syncthreads();
    }
    return tmp[tid] - v;
}

// ---- merged: chunk histograms + global total (blocks 0..NCH-1) + Wt/h precompute (rest) ----
// h holds ONLY the 128 x-channels (256 B/row). Wt rows 128..135 hold E_r[t] = emb[t] @ W_r[128:160]
// (type-fraction GEMM: emb contribution = frac @ E_r, done by the same K=160 MFMA; verified R8-R10).
__global__ __launch_bounds__(256) void k_prep(
    const float* __restrict__ x, const int* __restrict__ nt,
    const float* __restrict__ emb, const float* __restrict__ comp,
    const float* __restrict__ bases, const float* __restrict__ rootw,
    const int* __restrict__ ei,
    unsigned short* __restrict__ h, unsigned short* __restrict__ Wt,
    int* __restrict__ ghist, int* __restrict__ total) {
    __shared__ int hist[NBKT];
    int tid = threadIdx.x;
    int b = blockIdx.x;
    if (b < NCH) {
        for (int j = tid; j < NBKT; j += 256) hist[j] = 0;
        __syncthreads();
        int e0 = b * EPB;
        // batch-4 loads (R5/R10 evidence: breaks the load->atomic latency chain)
#pragma unroll
        for (int kk = 0; kk < 28; kk += 4) {
            int dv[4];
#pragma unroll
            for (int u = 0; u < 4; u++) {
                int i = (kk + u) * 256 + tid;
                dv[u] = (i < EPB) ? ei[NE + e0 + i] : -1;
            }
#pragma unroll
            for (int u = 0; u < 4; u++)
                if (dv[u] >= 0) atomicAdd(&hist[dv[u] >> 6], 1);
        }
        __syncthreads();
        int* g = ghist + (size_t)b * NBKT;
        for (int j = tid; j < NBKT; j += 256) {
            int v = hist[j];
            g[j] = v;
            if (v) atomicAdd(&total[j], v);    // total pre-zeroed by memset
        }
        return;
    }
    int idx = (b - NCH) * 256 + tid;
    if (idx < 9 * 128 * KW) {
        int ridx = idx / (128 * KW);
        int rem  = idx % (128 * KW);
        int o = rem / KW;
        int k = rem % KW;
        float v = 0.f;
        if (k < 128) {
            if (ridx < NR) {
#pragma unroll
                for (int bb = 0; bb < NBASES; bb++)
                    v += comp[ridx * NBASES + bb] * bases[(bb * FT + k) * OC + o];
            } else {
                v = rootw[k * OC + o];
            }
        } else if (k < 136) {
            int t = k - 128;                       // E row: emb[t] @ W[128:160]
            if (ridx < NR) {
#pragma unroll
                for (int bb = 0; bb < NBASES; bb++) {
                    float cb = comp[ridx * NBASES + bb], s2 = 0.f;
                    for (int k2 = 0; k2 < TE; k2++)
                        s2 += emb[t * TE + k2] * bases[(bb * FT + 128 + k2) * OC + o];
                    v += cb * s2;
                }
            } else {
                for (int k2 = 0; k2 < TE; k2++)
                    v += emb[t * TE + k2] * rootw[(128 + k2) * OC + o];
            }
        }                                          // k >= 136: zero pad
        Wt[idx] = (unsigned short)f2bf1(v);
    }
    if (idx < NN * 16) {
        int n = idx / 16, c = idx % 16;
        const float* p = x + (size_t)n * INC + c * 8;
        f32x4 v0 = *(const f32x4*)p, v1 = *(const f32x4*)(p + 4);
        uint4 o;
        o.x = f2bf1(v0.x) | (f2bf1(v0.y) << 16);
        o.y = f2bf1(v0.z) | (f2bf1(v0.w) << 16);
        o.z = f2bf1(v1.x) | (f2bf1(v1.y) << 16);
        o.w = f2bf1(v1.z) | (f2bf1(v1.w) << 16);
        *(uint4*)(h + (size_t)n * INC + c * 8) = o;
    }
}

// ---- merged scan + offsets: each of 7 blocks scans total in LDS; block 0 publishes bstart;
// each block then converts its 256 ghist columns to absolute chunk starts ----
__global__ __launch_bounds__(256) void k_scanoff(const int* __restrict__ total,
                                                 int* __restrict__ ghist,
                                                 int* __restrict__ bstart) {
    __shared__ int tot[NBKT];
    __shared__ int tmp[256];
    int tid = threadIdx.x;
    for (int j = tid; j < NBKT; j += 256) tot[j] = total[j];
    __syncthreads();
    int i0 = tid * 7, s = 0;
    int loc[7];
#pragma unroll
    for (int i = 0; i < 7; i++) {
        int j = i0 + i;
        loc[i] = (j < NBKT) ? tot[j] : 0;
        s += loc[i];
    }
    int run = bscan_excl(s, tmp);          // internal barriers cover the tot reads above
#pragma unroll
    for (int i = 0; i < 7; i++) {
        int j = i0 + i;
        if (j < NBKT) tot[j] = run;        // in-place exclusive prefix
        run += loc[i];
    }
    __syncthreads();
    if (blockIdx.x == 0) {
        for (int j = tid; j < NBKT; j += 256) bstart[j] = tot[j];
        if (tid == 0) bstart[NBKT] = NE;
    }
    int j = blockIdx.x * 256 + tid;
    if (j < NBKT) {
        int run2 = tot[j];
#pragma unroll 8
        for (int b = 0; b < NCH; b++) {
            int v = ghist[(size_t)b * NBKT + j];
            ghist[(size_t)b * NBKT + j] = run2;
            run2 += v;
        }
    }
}

// scatter packed entries (src | rel<<17 | dst_local<<20 | type<<26) into bucket-contiguous slots
__global__ __launch_bounds__(256) void k_scatter(const int* __restrict__ ei, const int* __restrict__ et,
                                                 const int* __restrict__ nt,
                                                 const int* __restrict__ ghist, unsigned* __restrict__ slots) {
    __shared__ int cur[NBKT];
    int tid = threadIdx.x, b = blockIdx.x;
    for (int j = tid; j < NBKT; j += 256) cur[j] = ghist[(size_t)b * NBKT + j];
    __syncthreads();
    int e0 = b * EPB;
#pragma unroll
    for (int kk = 0; kk < 28; kk += 4) {
        int sv[4], dv[4], rv[4], tv[4];
#pragma unroll
        for (int u = 0; u < 4; u++) {
            int i = (kk + u) * 256 + tid;
            int e = e0 + ((i < EPB) ? i : 0);
            sv[u] = ei[e]; dv[u] = ei[NE + e]; rv[u] = et[e];
            if (i >= EPB) dv[u] = -1;
        }
#pragma unroll
        for (int u = 0; u < 4; u++) tv[u] = nt[sv[u]];   // L2-resident 400KB table
#pragma unroll
        for (int u = 0; u < 4; u++) {
            if (dv[u] >= 0) {
                int pos = atomicAdd(&cur[dv[u] >> 6], 1);
                slots[pos] = (unsigned)sv[u] | ((unsigned)rv[u] << 17)
                           | ((unsigned)(dv[u] & 63) << 20) | ((unsigned)tv[u] << 26);
            }
        }
    }
}

// ---- fused: in-LDS (rel,node) 512-bin sort + TWO 32-node {agg|GEMM} dbuf pipelines + bias + ReLU ----
// Round-11: 64-node buckets (NBKT=1563) amortize bucket load + sort over two 32-node tiles; the
// agg/MFMA machinery per tile is R10's verbatim (batch-4 x 2x128B loads = 8 outstanding, type-frac).
// LDS = featmem 2x10752 + sl 6144 + pkl 2048 = 29696 B -> 5 blocks/CU. (256,5): VGPR cap ~100,
// live gather regs 16 -> no spill (R2/R6/R8 lesson: WRITE_SIZE is the tripwire).
__global__ __launch_bounds__(256, 5) void k_mega(
    const unsigned short* __restrict__ h, const int* __restrict__ nt,
    const float* __restrict__ bias,
    const unsigned short* __restrict__ Wt, const int* __restrict__ bstart,
    const unsigned* __restrict__ slots, float* __restrict__ out) {
    __shared__ unsigned short featmem[2][32 * KP];
    __shared__ unsigned sl[CAP];
    __shared__ unsigned pkl[512];

    const int tid = threadIdx.x;
    const int lane = tid & 63;
    const int wave = tid >> 6;
    const int j = blockIdx.x;
    const int n0 = j * TN;

    unsigned* sl_in = reinterpret_cast<unsigned*>(&featmem[0][0]); // CAP dwords (6144 B)
    int* hist = reinterpret_cast<int*>(&featmem[0][0]) + CAP;      // 512 ints
    int* tmp  = reinterpret_cast<int*>(&featmem[0][0]) + CAP + 512;// 256 ints (9216 B < 10752)

    // ---- phase 1: LDS counting sort by key = rel*64 + dst_local ----
    int s0 = bstart[j];
    int m = bstart[j + 1] - s0; if (m > CAP) m = CAP;
    for (int i = tid; i < m; i += 256) sl_in[i] = slots[s0 + i];
    hist[2 * tid] = 0; hist[2 * tid + 1] = 0;
    __syncthreads();
    for (int i = tid; i < m; i += 256) {
        unsigned v = sl_in[i];
        atomicAdd(&hist[((v >> 17) & 7u) * 64u + ((v >> 20) & 63u)], 1);
    }
    __syncthreads();
    int v0 = hist[2 * tid], v1 = hist[2 * tid + 1];
    int ex = bscan_excl(v0 + v1, tmp);                 // internal syncs cover hist reads
    pkl[2 * tid]     = (unsigned)ex | ((unsigned)v0 << 16);
    pkl[2 * tid + 1] = (unsigned)(ex + v0) | ((unsigned)v1 << 16);
    hist[2 * tid] = ex; hist[2 * tid + 1] = ex + v0;   // hist becomes scatter cursor
    __syncthreads();
    for (int i = tid; i < m; i += 256) {
        unsigned v = sl_in[i];
        int p = atomicAdd(&hist[((v >> 17) & 7u) * 64u + ((v >> 20) & 63u)], 1);
        sl[p] = (v & 0x1FFFFu) | (((v >> 26) & 7u) << 17);   // src + type (rel/dst dead post-sort)
    }
    // (sort scratch dead after the barrier inside the tile loop below)

    f32x4 acc[4];   // acc[rt*2+ct]

    auto mfma_pass = [&](int ridx, const unsigned short* fm) {  // B straight from global (L2-resident)
        const unsigned short* fA = fm + (lane & 15) * KP + ((lane >> 4) * 8);
        const unsigned short* gB = Wt + (size_t)ridx * 128 * KW
                                   + (wave * 32 + (lane & 15)) * KW + ((lane >> 4) * 8);
        __builtin_amdgcn_s_setprio(1);                 // T5: favor MFMA-entering wave
#pragma unroll
        for (int kc = 0; kc < 5; kc++) {
            bf16x8 a0 = *reinterpret_cast<const bf16x8*>(fA + 0 * 16 * KP + kc * 32);
            bf16x8 a1 = *reinterpret_cast<const bf16x8*>(fA + 1 * 16 * KP + kc * 32);
#pragma unroll
            for (int ct = 0; ct < 2; ct++) {
                bf16x8 b = *reinterpret_cast<const bf16x8*>(gB + ct * 16 * KW + kc * 32);
                acc[0 * 2 + ct] = __builtin_amdgcn_mfma_f32_16x16x32_bf16(a0, b, acc[0 * 2 + ct], 0, 0, 0);
                acc[1 * 2 + ct] = __builtin_amdgcn_mfma_f32_16x16x32_bf16(a1, b, acc[1 * 2 + ct], 0, 0, 0);
            }
        }
        __builtin_amdgcn_s_setprio(0);
    };

    // group g (16 lanes) streams its 2 nodes' rel-r edges. Lane l owns channels {4l..4l+3} and
    // {64+4l..64+4l+3}: TWO dwordx2 loads at bytes 8l and 128+8l of the 256B row -> 8 outstanding
    // loads per round (R10: the MLP lever). Type counts: lane l tracks types 2l,2l+1 in cnt2.
    const int g = tid >> 4, l = tid & 15;
    const unsigned* hw = reinterpret_cast<const unsigned*>(h);

    auto agg_pass = [&](int r, int t, unsigned short* fm) {
        int b0 = r * 64 + t * 32 + 2 * g;
        unsigned pk0 = pkl[b0], pk1 = pkl[b0 + 1];
        int sbeg = (int)(pk0 & 0xffffu);
        int e1 = (int)(pk1 & 0xffffu);                 // start of node1 == end of node0
        int send = e1 + (int)(pk1 >> 16);
        f32x2 sa[4];
#pragma unroll
        for (int i = 0; i < 4; i++) sa[i] = (f32x2){0.f, 0.f};
        f32x2 cnt2 = (f32x2){0.f, 0.f};
        float run = 0.f;
        for (int e = sbeg; e < send; e += 4) {
            uint2 wa[4], wb[4]; unsigned tpk = 0;
            // issue all 8 loads (clamped indices: always valid) before consuming any
#pragma unroll
            for (int u = 0; u < 4; u++) {
                int eu = e + u; if (eu >= send) eu = send - 1;
                unsigned v = sl[eu];
                const unsigned* hp = hw + (size_t)(v & 0x1FFFFu) * 64 + 2 * l;
                wa[u] = *reinterpret_cast<const uint2*>(hp);
                wb[u] = *reinterpret_cast<const uint2*>(hp + 32);
                tpk |= ((v >> 17) & 7u) << (3 * u);
            }
#pragma unroll
            for (int u = 0; u < 4; u++) {
                if (e + u < send) {
                    sa[0] += (f32x2){bflo(wa[u].x), bfhi(wa[u].x)};
                    sa[1] += (f32x2){bflo(wa[u].y), bfhi(wa[u].y)};
                    sa[2] += (f32x2){bflo(wb[u].x), bfhi(wb[u].x)};
                    sa[3] += (f32x2){bflo(wb[u].y), bfhi(wb[u].y)};
                    int tt = (int)((tpk >> (3 * u)) & 7u);
                    cnt2.x += (tt == 2 * l)     ? 1.f : 0.f;
                    cnt2.y += (tt == 2 * l + 1) ? 1.f : 0.f;
                    run += 1.f;
                    int nx = e + u + 1;
                    if (nx == e1 || nx == send) {      // end of some node's segment
                        int q = (e + u >= e1) ? 1 : 0;
                        float inv = __builtin_amdgcn_rcpf(run);
                        f32x2 m0 = sa[0] * inv, m1 = sa[1] * inv, m2 = sa[2] * inv,
                              m3 = sa[3] * inv, fr = cnt2 * inv;
                        unsigned* fp = reinterpret_cast<unsigned*>(fm + (2 * g + q) * KP);
                        uint2 oa, ob;
                        oa.x = cvtpk(m0.x, m0.y);
                        oa.y = cvtpk(m1.x, m1.y);
                        ob.x = cvtpk(m2.x, m2.y);
                        ob.y = cvtpk(m3.x, m3.y);
                        *reinterpret_cast<uint2*>(fp + 2 * l) = oa;
                        *reinterpret_cast<uint2*>(fp + 32 + 2 * l) = ob;
                        fp[64 + l] = cvtpk(fr.x, fr.y);
#pragma unroll
                        for (int i = 0; i < 4; i++) sa[i] = (f32x2){0.f, 0.f};
                        cnt2 = (f32x2){0.f, 0.f};
                        run = 0.f;
                    }
                }
            }
        }
#pragma unroll
        for (int q = 0; q < 2; q++) {                     // zero rows with no rel-r edges
            if ((pkl[b0 + q] >> 16) == 0u) {
                unsigned* fp = reinterpret_cast<unsigned*>(fm + (2 * g + q) * KP);
                *reinterpret_cast<uint2*>(fp + 2 * l) = (uint2){0u, 0u};
                *reinterpret_cast<uint2*>(fp + 32 + 2 * l) = (uint2){0u, 0u};
                fp[64 + l] = 0u;
            }
        }
    };

    const int rq = lane >> 4;
    for (int t = 0; t < 2; t++) {
        __syncthreads();   // t=0: sl/pkl final, sort scratch dead; t=1: all waves done with buf0

        // ---- stage tile t's root rows into buf0 ----
        // channels 0..127 = x; 128..135 = one-hot(node type) (exact); 136..159 = 0.
        for (int i = tid; i < 32 * 20; i += 256) {
            int nl = i / 20, c = i % 20, n = n0 + t * 32 + nl;
            uint4 v;
            if (c < 16) {
                // n may exceed NN-1 in the last bucket's tile 1: reads land in-workspace (ghist), discarded
                v = *reinterpret_cast<const uint4*>(h + (size_t)n * INC + c * 8);
            } else if (c == 16) {
                int tt = (n < NN) ? nt[n] : 0;      // bf16 1.0 = 0x3F80
                v.x = (tt == 0 ? 0x3F80u : 0u) | (tt == 1 ? 0x3F800000u : 0u);
                v.y = (tt == 2 ? 0x3F80u : 0u) | (tt == 3 ? 0x3F800000u : 0u);
                v.z = (tt == 4 ? 0x3F80u : 0u) | (tt == 5 ? 0x3F800000u : 0u);
                v.w = (tt == 6 ? 0x3F80u : 0u) | (tt == 7 ? 0x3F800000u : 0u);
            } else {
                v = (uint4){0u, 0u, 0u, 0u};
            }
            *reinterpret_cast<uint4*>(&featmem[0][nl * KP + c * 8]) = v;
        }
#pragma unroll
        for (int q = 0; q < 4; q++) acc[q] = (f32x4){0.f, 0.f, 0.f, 0.f};
        __syncthreads();   // root tile ready

        // pipeline: agg(r) fills buf[(r+1)&1] while waves retire mfma(r-1) on buf[r&1]; one bar/rel.
        int prev = 8;      // root
        for (int r = 0; r < NR; r++) {
            agg_pass(r, t, &featmem[(r + 1) & 1][0]);
            mfma_pass(prev, &featmem[r & 1][0]);
            prev = r;
            __syncthreads();
        }
        mfma_pass(7, &featmem[0][0]);   // agg(7) wrote buf0

        // ---- epilogue: bias + ReLU; C/D layout col=lane&15, row=(lane>>4)*4+i per 16x16 tile ----
#pragma unroll
        for (int ct = 0; ct < 2; ct++) {
            int col = wave * 32 + ct * 16 + (lane & 15);
            float bv = bias[col];
#pragma unroll
            for (int rt = 0; rt < 2; rt++) {
#pragma unroll
                for (int i = 0; i < 4; i++) {
                    int n = n0 + t * 32 + rt * 16 + rq * 4 + i;
                    if (n < NN) {
                        float v = acc[rt * 2 + ct][i] + bv;
                        out[(size_t)n * OC + col] = v > 0.f ? v : 0.f;
                    }
                }
            }
        }
    }
}

extern "C" void kernel_launch(void* const* d_in, const int* in_sizes, int n_in,
                              void* d_out, int out_size, void* d_ws, size_t ws_size,
                              hipStream_t stream) {
    const float* x     = (const float*)d_in[0];
    const int*   ntype = (const int*)d_in[1];
    const int*   ei    = (const int*)d_in[2];
    const int*   et    = (const int*)d_in[3];
    const float* emb   = (const float*)d_in[4];
    const float* bases = (const float*)d_in[5];
    const float* comp  = (const float*)d_in[6];
    const float* rootw = (const float*)d_in[7];
    const float* bias  = (const float*)d_in[8];
    float* out = (float*)d_out;

    char* ws = (char*)d_ws;
    // 256-aligned layout, ~34 MB total:
    unsigned short* Wt     = (unsigned short*)(ws);              // 368,640
    unsigned short* h      = (unsigned short*)(ws + 368640);     // 25,600,000 (NN x 128 bf16)
    int*            ghist  = (int*)(ws + 25968640);              // 1,600,512 B (256 x 1563 ints)
    int*            total  = (int*)(ws + 27569152);              // 6,400
    int*            bstart = (int*)(ws + 27575552);              // 6,400
    unsigned*       slots  = (unsigned*)(ws + 27581952);         // 6,400,000

    hipMemsetAsync(total, 0, NBKT * sizeof(int), stream);
    k_prep   <<<NCH + 6250, 256, 0, stream>>>(x, ntype, emb, comp, bases, rootw, ei, h, Wt, ghist, total);
    k_scanoff<<<7,    256, 0, stream>>>(total, ghist, bstart);
    k_scatter<<<NCH,  256, 0, stream>>>(ei, et, ntype, ghist, slots);
    k_mega   <<<NBKT, 256, 0, stream>>>(h, ntype, bias, Wt, bstart, slots, out);
}

// Round 12
// 338.646 us; speedup vs baseline: 1.0924x; 1.0924x over previous
//
#include <hip/hip_runtime.h>

#define NN 100000
#define NE 1600000
#define INC 128
#define TE 32
#define OC 128
#define NR 8
#define NBASES 8
#define FT 160
#define KP 168          // padded K stride (bf16 elems) for LDS feat tile
#define KW 160          // unpadded K stride for global Wt
#define TN 32           // nodes per mega block
#define NBKT 3125       // NN/32 dst buckets (exact)
#define NCH 256         // edge chunks (full-CU coverage)
#define EPB 6250        // edges per chunk (256*6250 = NE exactly)
#define CAP 896         // per-bucket edge cap (mean 512, +17 sigma)

typedef float f32x4 __attribute__((ext_vector_type(4)));
typedef float f32x2 __attribute__((ext_vector_type(2)));
typedef __bf16 bf16x8 __attribute__((ext_vector_type(8)));

__device__ __forceinline__ unsigned f2bf1(float f) {
    unsigned u = __float_as_uint(f);
    return (u + 0x7fffu + ((u >> 16) & 1u)) >> 16;   // RNE to bf16
}

__device__ __forceinline__ float bflo(unsigned u) { return __uint_as_float(u << 16); }
__device__ __forceinline__ float bfhi(unsigned u) { return __uint_as_float(u & 0xFFFF0000u); }

// pack two f32 -> bf16 pair (S0 -> low 16, S1 -> high 16), RNE — 1 instr
__device__ __forceinline__ unsigned cvtpk(float a, float b) {
    unsigned r;
    asm("v_cvt_pk_bf16_f32 %0, %1, %2" : "=v"(r) : "v"(a), "v"(b));
    return r;
}

// exclusive block scan over 256 per-thread values (Hillis-Steele in LDS)
__device__ __forceinline__ int bscan_excl(int v, int* tmp) {
    int tid = threadIdx.x;
    tmp[tid] = v; __syncthreads();
#pragma unroll
    for (int d = 1; d < 256; d <<= 1) {
        int t = (tid >= d) ? tmp[tid - d] : 0;
        __syncthreads();
        tmp[tid] += t;
        __syncthreads();
    }
    return tmp[tid] - v;
}

// ---- merged: chunk histograms + global total (blocks 0..NCH-1) + Wt/h precompute (rest) ----
// h holds ONLY the 128 x-channels (256 B/row). Wt rows 128..135 hold E_r[t] = emb[t] @ W_r[128:160]
// (type-fraction GEMM: emb contribution = frac @ E_r, done by the same K=160 MFMA; verified R8-R10).
__global__ __launch_bounds__(256) void k_prep(
    const float* __restrict__ x, const int* __restrict__ nt,
    const float* __restrict__ emb, const float* __restrict__ comp,
    const float* __restrict__ bases, const float* __restrict__ rootw,
    const int* __restrict__ ei,
    unsigned short* __restrict__ h, unsigned short* __restrict__ Wt,
    int* __restrict__ ghist, int* __restrict__ total) {
    __shared__ int hist[NBKT];
    int tid = threadIdx.x;
    int b = blockIdx.x;
    if (b < NCH) {
        for (int j = tid; j < NBKT; j += 256) hist[j] = 0;
        __syncthreads();
        int e0 = b * EPB;
        // batch-4 loads (R5/R10 evidence: breaks the load->atomic latency chain)
#pragma unroll
        for (int kk = 0; kk < 28; kk += 4) {
            int dv[4];
#pragma unroll
            for (int u = 0; u < 4; u++) {
                int i = (kk + u) * 256 + tid;
                dv[u] = (i < EPB) ? ei[NE + e0 + i] : -1;
            }
#pragma unroll
            for (int u = 0; u < 4; u++)
                if (dv[u] >= 0) atomicAdd(&hist[dv[u] >> 5], 1);
        }
        __syncthreads();
        int* g = ghist + (size_t)b * NBKT;
        for (int j = tid; j < NBKT; j += 256) {
            int v = hist[j];
            g[j] = v;
            if (v) atomicAdd(&total[j], v);    // total pre-zeroed by memset
        }
        return;
    }
    int idx = (b - NCH) * 256 + tid;
    if (idx < 9 * 128 * KW) {
        int ridx = idx / (128 * KW);
        int rem  = idx % (128 * KW);
        int o = rem / KW;
        int k = rem % KW;
        float v = 0.f;
        if (k < 128) {
            if (ridx < NR) {
#pragma unroll
                for (int bb = 0; bb < NBASES; bb++)
                    v += comp[ridx * NBASES + bb] * bases[(bb * FT + k) * OC + o];
            } else {
                v = rootw[k * OC + o];
            }
        } else if (k < 136) {
            int t = k - 128;                       // E row: emb[t] @ W[128:160]
            if (ridx < NR) {
#pragma unroll
                for (int bb = 0; bb < NBASES; bb++) {
                    float cb = comp[ridx * NBASES + bb], s2 = 0.f;
                    for (int k2 = 0; k2 < TE; k2++)
                        s2 += emb[t * TE + k2] * bases[(bb * FT + 128 + k2) * OC + o];
                    v += cb * s2;
                }
            } else {
                for (int k2 = 0; k2 < TE; k2++)
                    v += emb[t * TE + k2] * rootw[(128 + k2) * OC + o];
            }
        }                                          // k >= 136: zero pad
        Wt[idx] = (unsigned short)f2bf1(v);
    }
    if (idx < NN * 16) {
        int n = idx / 16, c = idx % 16;
        const float* p = x + (size_t)n * INC + c * 8;
        f32x4 v0 = *(const f32x4*)p, v1 = *(const f32x4*)(p + 4);
        uint4 o;
        o.x = f2bf1(v0.x) | (f2bf1(v0.y) << 16);
        o.y = f2bf1(v0.z) | (f2bf1(v0.w) << 16);
        o.z = f2bf1(v1.x) | (f2bf1(v1.y) << 16);
        o.w = f2bf1(v1.z) | (f2bf1(v1.w) << 16);
        *(uint4*)(h + (size_t)n * INC + c * 8) = o;
    }
}

// ---- single-block scan: total -> bstart (global bucket starts) ----
__global__ __launch_bounds__(256) void k_scan(const int* __restrict__ total,
                                              int* __restrict__ bstart) {
    __shared__ int tmp[256];
    int tid = threadIdx.x, s = 0, i0 = tid * 13;
    int loc[13];
#pragma unroll
    for (int i = 0; i < 13; i++) {
        int j = i0 + i;
        loc[i] = (j < NBKT) ? total[j] : 0;
        s += loc[i];
    }
    int run = bscan_excl(s, tmp);
#pragma unroll
    for (int i = 0; i < 13; i++) {
        int j = i0 + i;
        if (j < NBKT) { bstart[j] = run; run += loc[i]; }
    }
    if (tid == 0) bstart[NBKT] = NE;
}

// ---- wave-per-column offsets: replaces the 256-deep serial RMW chain of the old k_scanoff.
// Wave j: lane l loads ghist[b][j] for b=4l..4l+3 (independent L2-resident loads), 6-step
// __shfl_up wave scan + per-lane prefix, + bstart[j], write back. No serial chains. ----
__global__ __launch_bounds__(256) void k_off(int* __restrict__ ghist,
                                             const int* __restrict__ bstart) {
    int w = (blockIdx.x * 256 + threadIdx.x) >> 6;   // wave id = bucket column j
    int lane = threadIdx.x & 63;
    if (w >= NBKT) return;                           // whole wave exits together
    size_t base = (size_t)(lane * 4) * NBKT + w;
    int v[4];
#pragma unroll
    for (int k = 0; k < 4; k++) v[k] = ghist[base + (size_t)k * NBKT];
    int s = v[0] + v[1] + v[2] + v[3];
    int inc = s;
#pragma unroll
    for (int d = 1; d < 64; d <<= 1) {
        int t = __shfl_up(inc, d, 64);
        if (lane >= d) inc += t;
    }
    int run = bstart[w] + inc - s;                   // exclusive prefix for this lane's chunk 0
#pragma unroll
    for (int k = 0; k < 4; k++) {
        ghist[base + (size_t)k * NBKT] = run;
        run += v[k];
    }
}

// scatter packed entries (src | rel<<17 | dst_local<<20 | type<<25) into bucket-contiguous slots
__global__ __launch_bounds__(256) void k_scatter(const int* __restrict__ ei, const int* __restrict__ et,
                                                 const int* __restrict__ nt,
                                                 const int* __restrict__ ghist, unsigned* __restrict__ slots) {
    __shared__ int cur[NBKT];
    int tid = threadIdx.x, b = blockIdx.x;
    for (int j = tid; j < NBKT; j += 256) cur[j] = ghist[(size_t)b * NBKT + j];
    __syncthreads();
    int e0 = b * EPB;
#pragma unroll
    for (int kk = 0; kk < 28; kk += 4) {
        int sv[4], dv[4], rv[4], tv[4];
#pragma unroll
        for (int u = 0; u < 4; u++) {
            int i = (kk + u) * 256 + tid;
            int e = e0 + ((i < EPB) ? i : 0);
            sv[u] = ei[e]; dv[u] = ei[NE + e]; rv[u] = et[e];
            if (i >= EPB) dv[u] = -1;
        }
#pragma unroll
        for (int u = 0; u < 4; u++) tv[u] = nt[sv[u]];   // L2-resident 400KB table
#pragma unroll
        for (int u = 0; u < 4; u++) {
            if (dv[u] >= 0) {
                int pos = atomicAdd(&cur[dv[u] >> 5], 1);
                slots[pos] = (unsigned)sv[u] | ((unsigned)rv[u] << 17)
                           | ((unsigned)(dv[u] & 31) << 20) | ((unsigned)tv[u] << 25);
            }
        }
    }
}

// ---- fused: in-LDS (rel,node) sort + double-buffered {aggregate | GEMM} pipeline + bias + ReLU ----
// R10 verbatim (156.6 us best). 6 blocks/CU is a HARD requirement (R11: 5 blocks -> occ 37.7%,
// 197 us): LDS must stay <= 26.6 KB. Gather: batch-4 x TWO 128B-apart dwordx2 loads = 8
// outstanding/lane (the MLP lever, R9/R10 isolated). Type-fraction channels do emb via MFMA.
// LDS = featmem 2x10752 + sl 3584 + pkl 1024 = 26112 B -> 6 blocks/CU.
__global__ __launch_bounds__(256, 6) void k_mega(
    const unsigned short* __restrict__ h, const int* __restrict__ nt,
    const float* __restrict__ bias,
    const unsigned short* __restrict__ Wt, const int* __restrict__ bstart,
    const unsigned* __restrict__ slots, float* __restrict__ out) {
    __shared__ unsigned short featmem[2][TN * KP];
    __shared__ unsigned sl[CAP];
    __shared__ unsigned pkl[256];

    const int tid = threadIdx.x;
    const int lane = tid & 63;
    const int wave = tid >> 6;
    const int j = blockIdx.x;
    const int n0 = j * TN;

    unsigned* sl_in = reinterpret_cast<unsigned*>(&featmem[0][0]); // CAP dwords (3584 B)
    int* hist = reinterpret_cast<int*>(&featmem[0][0]) + CAP;      // 256 ints
    int* tmp  = reinterpret_cast<int*>(&featmem[0][0]) + CAP + 256;// 256 ints

    // ---- phase 1: LDS counting sort by key = rel*32 + dst_local ----
    int s0 = bstart[j];
    int m = bstart[j + 1] - s0; if (m > CAP) m = CAP;
    for (int i = tid; i < m; i += 256) sl_in[i] = slots[s0 + i];
    hist[tid] = 0;
    __syncthreads();
    for (int i = tid; i < m; i += 256) {
        unsigned v = sl_in[i];
        atomicAdd(&hist[((v >> 17) & 7u) * 32u + ((v >> 20) & 31u)], 1);
    }
    __syncthreads();
    int v0 = hist[tid];
    int ex = bscan_excl(v0, tmp);                      // internal syncs cover hist reads
    pkl[tid] = (unsigned)ex | ((unsigned)v0 << 16);
    hist[tid] = ex;                                    // hist becomes scatter cursor
    __syncthreads();
    for (int i = tid; i < m; i += 256) {
        unsigned v = sl_in[i];
        int p = atomicAdd(&hist[((v >> 17) & 7u) * 32u + ((v >> 20) & 31u)], 1);
        sl[p] = (v & 0x1FFFFu) | (((v >> 25) & 7u) << 17);   // src + type (rel dead post-sort)
    }
    __syncthreads();

    // ---- phase 2: root feat tile into buf0 (sort scratch dead) ----
    // channels 0..127 = x; 128..135 = one-hot(node type) (exact); 136..159 = 0.
    for (int i = tid; i < TN * 20; i += 256) {
        int nl = i / 20, c = i % 20, n = n0 + nl;
        uint4 v;
        if (c < 16) {
            v = *reinterpret_cast<const uint4*>(h + (size_t)n * INC + c * 8);
        } else if (c == 16) {
            int t = nt[n];                  // bf16 1.0 = 0x3F80
            v.x = (t == 0 ? 0x3F80u : 0u) | (t == 1 ? 0x3F800000u : 0u);
            v.y = (t == 2 ? 0x3F80u : 0u) | (t == 3 ? 0x3F800000u : 0u);
            v.z = (t == 4 ? 0x3F80u : 0u) | (t == 5 ? 0x3F800000u : 0u);
            v.w = (t == 6 ? 0x3F80u : 0u) | (t == 7 ? 0x3F800000u : 0u);
        } else {
            v = (uint4){0u, 0u, 0u, 0u};
        }
        *reinterpret_cast<uint4*>(&featmem[0][nl * KP + c * 8]) = v;
    }

    f32x4 acc[4];   // acc[rt*2+ct]
#pragma unroll
    for (int t = 0; t < 4; t++) acc[t] = (f32x4){0.f, 0.f, 0.f, 0.f};

    auto mfma_pass = [&](int ridx, const unsigned short* fm) {  // B straight from global (L2-resident)
        const unsigned short* fA = fm + (lane & 15) * KP + ((lane >> 4) * 8);
        const unsigned short* gB = Wt + (size_t)ridx * 128 * KW
                                   + (wave * 32 + (lane & 15)) * KW + ((lane >> 4) * 8);
#pragma unroll
        for (int kc = 0; kc < 5; kc++) {
            bf16x8 a0 = *reinterpret_cast<const bf16x8*>(fA + 0 * 16 * KP + kc * 32);
            bf16x8 a1 = *reinterpret_cast<const bf16x8*>(fA + 1 * 16 * KP + kc * 32);
#pragma unroll
            for (int ct = 0; ct < 2; ct++) {
                bf16x8 b = *reinterpret_cast<const bf16x8*>(gB + ct * 16 * KW + kc * 32);
                acc[0 * 2 + ct] = __builtin_amdgcn_mfma_f32_16x16x32_bf16(a0, b, acc[0 * 2 + ct], 0, 0, 0);
                acc[1 * 2 + ct] = __builtin_amdgcn_mfma_f32_16x16x32_bf16(a1, b, acc[1 * 2 + ct], 0, 0, 0);
            }
        }
    };

    // group g (16 lanes) streams its 2 nodes' rel-r edges. Lane l owns channels {4l..4l+3} and
    // {64+4l..64+4l+3}: TWO dwordx2 loads at bytes 8l and 128+8l of the 256B row (each load is a
    // fully-coalesced 128B wave-request; 128B apart so never merged). Type counts: lane l tracks
    // types 2l,2l+1 in cnt2 (frac channels 128+2l,129+2l; lanes>=4 auto-zero).
    const int g = tid >> 4, l = tid & 15;
    const unsigned* hw = reinterpret_cast<const unsigned*>(h);

    auto agg_pass = [&](int r, unsigned short* fm) {
        int b0 = r * 32 + 2 * g;
        unsigned pk0 = pkl[b0], pk1 = pkl[b0 + 1];
        int sbeg = (int)(pk0 & 0xffffu);
        int e1 = (int)(pk1 & 0xffffu);                 // start of node1 == end of node0
        int send = e1 + (int)(pk1 >> 16);
        f32x2 sa[4];
#pragma unroll
        for (int i = 0; i < 4; i++) sa[i] = (f32x2){0.f, 0.f};
        f32x2 cnt2 = (f32x2){0.f, 0.f};
        float run = 0.f;
        for (int e = sbeg; e < send; e += 4) {
            uint2 wa[4], wb[4]; unsigned tpk = 0;
            // issue all 8 loads (clamped indices: always valid) before consuming any
#pragma unroll
            for (int u = 0; u < 4; u++) {
                int eu = e + u; if (eu >= send) eu = send - 1;
                unsigned v = sl[eu];
                const unsigned* hp = hw + (size_t)(v & 0x1FFFFu) * 64 + 2 * l;
                wa[u] = *reinterpret_cast<const uint2*>(hp);
                wb[u] = *reinterpret_cast<const uint2*>(hp + 32);
                tpk |= ((v >> 17) & 7u) << (3 * u);
            }
#pragma unroll
            for (int u = 0; u < 4; u++) {
                if (e + u < send) {
                    sa[0] += (f32x2){bflo(wa[u].x), bfhi(wa[u].x)};
                    sa[1] += (f32x2){bflo(wa[u].y), bfhi(wa[u].y)};
                    sa[2] += (f32x2){bflo(wb[u].x), bfhi(wb[u].x)};
                    sa[3] += (f32x2){bflo(wb[u].y), bfhi(wb[u].y)};
                    int tt = (int)((tpk >> (3 * u)) & 7u);
                    cnt2.x += (tt == 2 * l)     ? 1.f : 0.f;
                    cnt2.y += (tt == 2 * l + 1) ? 1.f : 0.f;
                    run += 1.f;
                    int nx = e + u + 1;
                    if (nx == e1 || nx == send) {      // end of some node's segment
                        int q = (e + u >= e1) ? 1 : 0;
                        float inv = __builtin_amdgcn_rcpf(run);
                        f32x2 m0 = sa[0] * inv, m1 = sa[1] * inv, m2 = sa[2] * inv,
                              m3 = sa[3] * inv, fr = cnt2 * inv;
                        unsigned* fp = reinterpret_cast<unsigned*>(fm + (2 * g + q) * KP);
                        uint2 oa, ob;
                        oa.x = cvtpk(m0.x, m0.y);
                        oa.y = cvtpk(m1.x, m1.y);
                        ob.x = cvtpk(m2.x, m2.y);
                        ob.y = cvtpk(m3.x, m3.y);
                        *reinterpret_cast<uint2*>(fp + 2 * l) = oa;
                        *reinterpret_cast<uint2*>(fp + 32 + 2 * l) = ob;
                        fp[64 + l] = cvtpk(fr.x, fr.y);
#pragma unroll
                        for (int i = 0; i < 4; i++) sa[i] = (f32x2){0.f, 0.f};
                        cnt2 = (f32x2){0.f, 0.f};
                        run = 0.f;
                    }
                }
            }
        }
#pragma unroll
        for (int q = 0; q < 2; q++) {                     // zero rows with no rel-r edges
            if ((pkl[b0 + q] >> 16) == 0u) {
                unsigned* fp = reinterpret_cast<unsigned*>(fm + (2 * g + q) * KP);
                *reinterpret_cast<uint2*>(fp + 2 * l) = (uint2){0u, 0u};
                *reinterpret_cast<uint2*>(fp + 32 + 2 * l) = (uint2){0u, 0u};
                fp[64 + l] = 0u;
            }
        }
    };

    __syncthreads();   // root feat tile ready
    // pipeline: agg(r) fills buf[(r+1)&1] while waves retire mfma(r-1) on buf[r&1]; one bar/rel.
    int prev = 8;      // root
    for (int r = 0; r < NR; r++) {
        agg_pass(r, &featmem[(r + 1) & 1][0]);
        mfma_pass(prev, &featmem[r & 1][0]);
        prev = r;
        __syncthreads();
    }
    mfma_pass(7, &featmem[0][0]);   // agg(7) wrote buf0

    // ---- epilogue: bias + ReLU; C/D layout col=lane&15, row=(lane>>4)*4+i per 16x16 tile ----
    const int rq = lane >> 4;
#pragma unroll
    for (int ct = 0; ct < 2; ct++) {
        int col = wave * 32 + ct * 16 + (lane & 15);
        float bv = bias[col];
#pragma unroll
        for (int rt = 0; rt < 2; rt++) {
#pragma unroll
            for (int i = 0; i < 4; i++) {
                int n = n0 + rt * 16 + rq * 4 + i;
                float v = acc[rt * 2 + ct][i] + bv;
                out[(size_t)n * OC + col] = v > 0.f ? v : 0.f;
            }
        }
    }
}

extern "C" void kernel_launch(void* const* d_in, const int* in_sizes, int n_in,
                              void* d_out, int out_size, void* d_ws, size_t ws_size,
                              hipStream_t stream) {
    const float* x     = (const float*)d_in[0];
    const int*   ntype = (const int*)d_in[1];
    const int*   ei    = (const int*)d_in[2];
    const int*   et    = (const int*)d_in[3];
    const float* emb   = (const float*)d_in[4];
    const float* bases = (const float*)d_in[5];
    const float* comp  = (const float*)d_in[6];
    const float* rootw = (const float*)d_in[7];
    const float* bias  = (const float*)d_in[8];
    float* out = (float*)d_out;

    char* ws = (char*)d_ws;
    // 256-aligned layout, ~35.6 MB total:
    unsigned short* Wt     = (unsigned short*)(ws);              // 368,640
    unsigned short* h      = (unsigned short*)(ws + 368640);     // 25,600,000 (NN x 128 bf16)
    int*            ghist  = (int*)(ws + 25968640);              // 3,200,000 B (256 x 3125 ints)
    int*            total  = (int*)(ws + 29168640);              // 12,544
    int*            bstart = (int*)(ws + 29181184);              // 12,544
    unsigned*       slots  = (unsigned*)(ws + 29193728);         // 6,400,000

    hipMemsetAsync(total, 0, NBKT * sizeof(int), stream);
    k_prep   <<<NCH + 6250, 256, 0, stream>>>(x, ntype, emb, comp, bases, rootw, ei, h, Wt, ghist, total);
    k_scan   <<<1,    256, 0, stream>>>(total, bstart);
    k_off    <<<782,  256, 0, stream>>>(ghist, bstart);
    k_scatter<<<NCH,  256, 0, stream>>>(ei, et, ntype, ghist, slots);
    k_mega   <<<NBKT, 256, 0, stream>>>(h, ntype, bias, Wt, bstart, slots, out);
}